// Round 1
// baseline (275.509 us; speedup 1.0000x reference)
//
#include <hip/hip_runtime.h>
#include <hip/hip_bf16.h>

typedef __attribute__((ext_vector_type(8))) short short8;
typedef __attribute__((ext_vector_type(4))) short short4v;
typedef __attribute__((ext_vector_type(4))) float f32x4;
typedef __attribute__((ext_vector_type(2))) float f32x2;

// Sizes (fixed by the problem)
// X: (32, 256, 64, 64) f32 ; W,B: (256, 256, 2, 2) f32 ; out: (32, 256, 128, 128) f32
// GEMM view: M = 131072 pixels, N = 1024 (col = o*4 + kh*2 + kw), K = 256.

__device__ __forceinline__ short f2bf(float f) {
    __hip_bfloat16 h = __float2bfloat16(f);
    union { __hip_bfloat16 h; short s; } u; u.h = h; return u.s;
}

// bsum[o*4+kl] = sum_c biases[o][c][kl]
__global__ __launch_bounds__(64) void prep_bias(const float* __restrict__ B, float* __restrict__ bsum) {
    const int o = blockIdx.x;      // 0..255
    const int t = threadIdx.x;     // 0..63
    float acc0 = 0.f, acc1 = 0.f, acc2 = 0.f, acc3 = 0.f;
    for (int c = t; c < 256; c += 64) {
        f32x4 v = *(const f32x4*)(B + ((size_t)o << 10) + ((size_t)c << 2));
        acc0 += v[0]; acc1 += v[1]; acc2 += v[2]; acc3 += v[3];
    }
    #pragma unroll
    for (int off = 32; off >= 1; off >>= 1) {
        acc0 += __shfl_down(acc0, off, 64);
        acc1 += __shfl_down(acc1, off, 64);
        acc2 += __shfl_down(acc2, off, 64);
        acc3 += __shfl_down(acc3, off, 64);
    }
    if (t == 0) {
        bsum[(o << 2) + 0] = acc0;
        bsum[(o << 2) + 1] = acc1;
        bsum[(o << 2) + 2] = acc2;
        bsum[(o << 2) + 3] = acc3;
    }
}

// Block tile: BM=128 pixels x BN=256 cols, BK=32, 8 waves (2x4), wave tile 64x64.
__global__ __launch_bounds__(512, 4) void deconv_gemm(
    const float* __restrict__ X, const float* __restrict__ W,
    const float* __restrict__ Bsum, float* __restrict__ Y)
{
    __shared__ float As[32][130];   // f32, pad +2 -> conflict-free strided b32 frag reads
    __shared__ short Bs[256][40];   // bf16 bits, row = 80 B

    const int tid = threadIdx.x;
    const int bid = blockIdx.x;
    const int cb  = bid & 3;        // col tile (fastest -> adjacent blocks share A tile)
    const int rb  = bid >> 2;       // row tile 0..1023
    const int p0  = rb << 7;        // global pixel base (multiple of 128)
    const int n   = p0 >> 12;       // image
    const int q0  = p0 & 4095;      // pixel within image (multiple of 128)
    const int o0  = cb << 6;        // o base (64 o's per col tile)

    const int wave = tid >> 6, lane = tid & 63;
    const int wm = wave >> 2, wn = wave & 3;    // 2x4 wave grid
    const int l15 = lane & 15, g = lane >> 4;   // frag row/col idx, k-group

    f32x4 acc[4][4] = {};

    // A staging: thread covers k = tid>>4 (one of 32), m = (tid&15)*4 + {0..3, 64..67}
    const int ak = tid >> 4;
    const int am = (tid & 15) << 2;
    const float* xp = X + ((size_t)n << 20) + ((size_t)ak << 12) + (size_t)(q0 + am);
    // B staging: thread covers o_local = tid>>3, c' = (tid&7)*4 + i (i=0..3), all 4 kl
    const int bol = tid >> 3;
    const int bc  = (tid & 7) << 2;
    const float* wp = W + ((size_t)(o0 + bol) << 10) + ((size_t)bc << 2);

    for (int c0 = 0; c0 < 256; c0 += 32) {
        // global loads first (latency overlaps previous compute tail)
        f32x4 a0  = *(const f32x4*)(xp + ((size_t)c0 << 12));
        f32x4 a1  = *(const f32x4*)(xp + ((size_t)c0 << 12) + 64);
        f32x4 wv0 = *(const f32x4*)(wp + (c0 << 2));
        f32x4 wv1 = *(const f32x4*)(wp + (c0 << 2) + 4);
        f32x4 wv2 = *(const f32x4*)(wp + (c0 << 2) + 8);
        f32x4 wv3 = *(const f32x4*)(wp + (c0 << 2) + 12);

        __syncthreads();   // previous tile fully consumed

        *(f32x2*)&As[ak][am]      = (f32x2){a0[0], a0[1]};
        *(f32x2*)&As[ak][am + 2]  = (f32x2){a0[2], a0[3]};
        *(f32x2*)&As[ak][am + 64] = (f32x2){a1[0], a1[1]};
        *(f32x2*)&As[ak][am + 66] = (f32x2){a1[2], a1[3]};
        #pragma unroll
        for (int kl = 0; kl < 4; ++kl) {
            short4v s = (short4v){ f2bf(wv0[kl]), f2bf(wv1[kl]), f2bf(wv2[kl]), f2bf(wv3[kl]) };
            *(short4v*)&Bs[(bol << 2) + kl][bc] = s;
        }

        __syncthreads();   // tile visible

        short8 bfr[4];
        #pragma unroll
        for (int fn = 0; fn < 4; ++fn)
            bfr[fn] = *(const short8*)&Bs[(wn << 6) + (fn << 4) + l15][g << 3];

        #pragma unroll
        for (int fm = 0; fm < 4; ++fm) {
            const int m = (wm << 6) + (fm << 4) + l15;
            short8 afr;
            #pragma unroll
            for (int j = 0; j < 8; ++j) afr[j] = f2bf(As[(g << 3) + j][m]);
            #pragma unroll
            for (int fn = 0; fn < 4; ++fn)
                acc[fm][fn] = __builtin_amdgcn_mfma_f32_16x16x32_bf16(afr, bfr[fn], acc[fm][fn], 0, 0, 0);
        }
        __syncthreads();
    }

    // Epilogue: D frag (r) -> pixel = wm*64 + fm*16 + 4g + r, col = cb*256 + wn*64 + fn*16 + l15.
    // Pair-swap with lane^1 merges kw=0/kw=1 so each lane stores one contiguous float4.
    const int ih = (q0 >> 6) + wm;
    #pragma unroll
    for (int fn = 0; fn < 4; ++fn) {
        const int col = (cb << 8) + (wn << 6) + (fn << 4) + l15;
        const float bv = Bsum[col];
        const int o = col >> 2;
        const int h = (ih << 1) + ((col >> 1) & 1);
        float* yrow = Y + ((((size_t)n << 8) + (size_t)o) << 14) + ((size_t)h << 7);
        #pragma unroll
        for (int fm = 0; fm < 4; ++fm) {
            const float v0 = acc[fm][fn][0] + bv;
            const float v1 = acc[fm][fn][1] + bv;
            const float v2 = acc[fm][fn][2] + bv;
            const float v3 = acc[fm][fn][3] + bv;
            const float p0v = __shfl_xor(v0, 1, 64);
            const float p1v = __shfl_xor(v1, 1, 64);
            const float p2v = __shfl_xor(v2, 1, 64);
            const float p3v = __shfl_xor(v3, 1, 64);
            const int iw0 = (fm << 4) + (g << 2);
            f32x4 st; int w;
            if (!(lane & 1)) { st = (f32x4){v0, p0v, v1, p1v}; w = (iw0 << 1); }
            else             { st = (f32x4){p2v, v2, p3v, v3}; w = (iw0 << 1) + 4; }
            *(f32x4*)(yrow + w) = st;
        }
    }
}

extern "C" void kernel_launch(void* const* d_in, const int* in_sizes, int n_in,
                              void* d_out, int out_size, void* d_ws, size_t ws_size,
                              hipStream_t stream) {
    const float* X = (const float*)d_in[0];   // batches (32,256,64,64)
    const float* W = (const float*)d_in[1];   // weights (256,256,2,2)
    const float* B = (const float*)d_in[2];   // biases  (256,256,2,2)
    float* bsum = (float*)d_ws;               // 4 KiB scratch
    prep_bias<<<256, 64, 0, stream>>>(B, bsum);
    deconv_gemm<<<4096, 512, 0, stream>>>(X, W, bsum, (float*)d_out);
}